// Round 14
// baseline (233.607 us; speedup 1.0000x reference)
//
#include <hip/hip_runtime.h>
#include <math.h>

#define D      256
#define NSEC   10
#define EPS    1e-6f
#define SLICE  0.1f

// ws float layout
#define WS_SUMS 0                      // [0,2560) per-sector sums
#define WS_CNT  (NSEC * D)             // [2560,2570) per-sector counts
#define WS_PART (NSEC * D + NSEC)      // [2570,3594) per-block distance partials (1024)
#define WS_WARM (NSEC * D + NSEC + 1024) // [3594,4618) warm-probe dummy outputs
#define WS_ZERO_FLOATS (NSEC * D + NSEC)

#define WARM_SWEEPS 9   // FORENSIC: push k_warm9 above the ~115us harness fills

__global__ void k_zero(float* __restrict__ ws) {
    int i = blockIdx.x * blockDim.x + threadIdx.x;
    if (i < WS_ZERO_FLOATS) ws[i] = 0.f;
}

// ---- k_sums: unchanged ----
__global__ __launch_bounds__(256) void k_sums(const float* __restrict__ emb,
                                              const int* __restrict__ sec,
                                              float* __restrict__ ws, int nrows) {
    const int lane = threadIdx.x & 63;
    const int wid  = threadIdx.x >> 6;
    const int gw   = blockIdx.x * 4 + wid;
    const int nw   = gridDim.x * 4;

    float4 acc[NSEC];
    float  cnt[NSEC];
#pragma unroll
    for (int s = 0; s < NSEC; ++s) { acc[s] = make_float4(0.f, 0.f, 0.f, 0.f); cnt[s] = 0.f; }

    const float* ep = emb + (size_t)lane * 4;

    auto accum = [&](int sv, float4 v) {
        const int s = __builtin_amdgcn_readfirstlane(sv);
#pragma unroll
        for (int ss = 0; ss < NSEC; ++ss) {
            if (s == ss) {
                acc[ss].x += v.x; acc[ss].y += v.y; acc[ss].z += v.z; acc[ss].w += v.w;
                cnt[ss] += 1.f;
            }
        }
    };

    int r = gw;
    for (; r + 3 * nw < nrows; r += 4 * nw) {
        const int s0 = sec[r];
        const int s1 = sec[r + nw];
        const int s2 = sec[r + 2 * nw];
        const int s3 = sec[r + 3 * nw];
        const float4 v0 = *reinterpret_cast<const float4*>(ep + (size_t)r * D);
        const float4 v1 = *reinterpret_cast<const float4*>(ep + (size_t)(r + nw) * D);
        const float4 v2 = *reinterpret_cast<const float4*>(ep + (size_t)(r + 2 * nw) * D);
        const float4 v3 = *reinterpret_cast<const float4*>(ep + (size_t)(r + 3 * nw) * D);
        accum(s0, v0); accum(s1, v1); accum(s2, v2); accum(s3, v3);
    }
    for (; r < nrows; r += nw)
        accum(sec[r], *reinterpret_cast<const float4*>(ep + (size_t)r * D));

    __shared__ float lsum[NSEC * D];
    __shared__ float lcnt[NSEC];
    for (int i = threadIdx.x; i < NSEC * D; i += 256) lsum[i] = 0.f;
    if (threadIdx.x < NSEC) lcnt[threadIdx.x] = 0.f;
    __syncthreads();

    for (int w = 0; w < 4; ++w) {
        if (wid == w) {
#pragma unroll
            for (int ss = 0; ss < NSEC; ++ss) {
                float* p = &lsum[ss * D + lane * 4];
                p[0] += acc[ss].x; p[1] += acc[ss].y; p[2] += acc[ss].z; p[3] += acc[ss].w;
                if (lane == 0) lcnt[ss] += cnt[ss];
            }
        }
        __syncthreads();
    }

#pragma unroll
    for (int ss = 0; ss < NSEC; ++ss)
        atomicAdd(&ws[WS_SUMS + ss * D + threadIdx.x], lsum[ss * D + threadIdx.x]);
    if (threadIdx.x < NSEC)
        atomicAdd(&ws[WS_CNT + threadIdx.x], lcnt[threadIdx.x]);
}

// FORENSIC PROBE: pure temb stream, 9 sweeps, k_sums' load pattern. Direct
// counter row => cold-stream rate, first-sweep premium, L3 retention (FETCH).
__global__ __launch_bounds__(256) void k_warm9(const float* __restrict__ temb,
                                               float* __restrict__ dummy, int nrows) {
    const int lane = threadIdx.x & 63;
    const int wid  = threadIdx.x >> 6;
    const int gw   = blockIdx.x * 4 + wid;
    const int nw   = gridDim.x * 4;
    const float* tp = temb + (size_t)lane * 4;

    float ax = 0.f, ay = 0.f, az = 0.f, aw = 0.f;
#pragma unroll 1
    for (int sweep = 0; sweep < WARM_SWEEPS; ++sweep) {
        int r = gw;
        for (; r + 3 * nw < nrows; r += 4 * nw) {
            const float4 v0 = *reinterpret_cast<const float4*>(tp + (size_t)r * D);
            const float4 v1 = *reinterpret_cast<const float4*>(tp + (size_t)(r + nw) * D);
            const float4 v2 = *reinterpret_cast<const float4*>(tp + (size_t)(r + 2 * nw) * D);
            const float4 v3 = *reinterpret_cast<const float4*>(tp + (size_t)(r + 3 * nw) * D);
            ax += v0.x + v1.x + v2.x + v3.x;
            ay += v0.y + v1.y + v2.y + v3.y;
            az += v0.z + v1.z + v2.z + v3.z;
            aw += v0.w + v1.w + v2.w + v3.w;
        }
        for (; r < nrows; r += nw) {
            const float4 v = *reinterpret_cast<const float4*>(tp + (size_t)r * D);
            ax += v.x; ay += v.y; az += v.z; aw += v.w;
        }
    }

    float a = ax + ay + az + aw;
#pragma unroll
    for (int off = 32; off >= 1; off >>= 1) a += __shfl_xor(a, off, 64);
    __shared__ float wsum[4];
    if (lane == 0) wsum[wid] = a;
    __syncthreads();
    if (threadIdx.x == 0)
        dummy[blockIdx.x] = wsum[0] + wsum[1] + wsum[2] + wsum[3];  // keep reads live
}

// k_dist4: unchanged from R13
__global__ __launch_bounds__(256, 4) void k_dist4(const float* __restrict__ temb,
                                                  const float* __restrict__ tsl,
                                                  const float* __restrict__ ws,
                                                  float* __restrict__ part, int nrows) {
    __shared__ float lc[NSEC * D];
    for (int i = threadIdx.x; i < NSEC * D; i += 256) {
        const int s = i >> 8;
        lc[i] = ws[WS_SUMS + i] / ws[WS_CNT + s];
    }
    __syncthreads();

    const int lane = threadIdx.x & 63;
    const int wid  = threadIdx.x >> 6;
    const int gw   = blockIdx.x * 4 + wid;
    const int nw   = gridDim.x * 4;

    const float* tp = temb + (size_t)lane * 4;

    float wacc = 0.f;
    int r = gw;
    for (; r + 7 * nw < nrows; r += 8 * nw) {
        float  t[8];
        float4 v[8];
#pragma unroll
        for (int k = 0; k < 8; ++k) t[k] = tsl[r + k * nw];
#pragma unroll
        for (int k = 0; k < 8; ++k)
            v[k] = *reinterpret_cast<const float4*>(tp + (size_t)(r + k * nw) * D);

        asm volatile("" ::: "memory");

        float l[8];
#pragma unroll
        for (int k = 0; k < 8; ++k) {
            int s = (int)floorf(t[k] / SLICE);
            s = s < 0 ? 0 : (s > NSEC - 1 ? NSEC - 1 : s);
            const float4 c = *reinterpret_cast<const float4*>(&lc[s * D + lane * 4]);
            const float dx = v[k].x - c.x + EPS;
            const float dy = v[k].y - c.y + EPS;
            const float dz = v[k].z - c.z + EPS;
            const float dw = v[k].w - c.w + EPS;
            l[k] = dx * dx + dy * dy + dz * dz + dw * dw;
        }

#pragma unroll
        for (int off = 32; off >= 1; off >>= 1) {
#pragma unroll
            for (int k = 0; k < 8; ++k) l[k] += __shfl_xor(l[k], off, 64);
        }
#pragma unroll
        for (int k = 0; k < 8; ++k) wacc += sqrtf(l[k]);
    }
    for (; r < nrows; r += nw) {
        const float si = tsl[r];
        int s = (int)floorf(si / SLICE);
        s = s < 0 ? 0 : (s > NSEC - 1 ? NSEC - 1 : s);
        const float4 vv = *reinterpret_cast<const float4*>(tp + (size_t)r * D);
        const float4 c = *reinterpret_cast<const float4*>(&lc[s * D + lane * 4]);
        const float dx = vv.x - c.x + EPS;
        const float dy = vv.y - c.y + EPS;
        const float dz = vv.z - c.z + EPS;
        const float dw = vv.w - c.w + EPS;
        float loc = dx * dx + dy * dy + dz * dz + dw * dw;
#pragma unroll
        for (int off = 32; off >= 1; off >>= 1) loc += __shfl_xor(loc, off, 64);
        wacc += sqrtf(loc);
    }

    __shared__ float wsum[4];
    if (lane == 0) wsum[wid] = wacc;
    __syncthreads();
    if (threadIdx.x == 0)
        part[blockIdx.x] = wsum[0] + wsum[1] + wsum[2] + wsum[3];
}

__global__ __launch_bounds__(1024) void k_final(const float* __restrict__ part,
                                                float* __restrict__ out,
                                                int nparts, float invN) {
    float v = 0.f;
    for (int i = threadIdx.x; i < nparts; i += 1024) v += part[i];
#pragma unroll
    for (int off = 32; off >= 1; off >>= 1) v += __shfl_xor(v, off, 64);
    __shared__ float s16[16];
    if ((threadIdx.x & 63) == 0) s16[threadIdx.x >> 6] = v;
    __syncthreads();
    if (threadIdx.x == 0) {
        float tot = 0.f;
#pragma unroll
        for (int k = 0; k < 16; ++k) tot += s16[k];
        out[0] = tot * invN;
    }
}

extern "C" void kernel_launch(void* const* d_in, const int* in_sizes, int n_in,
                              void* d_out, int out_size, void* d_ws, size_t ws_size,
                              hipStream_t stream) {
    const float* semb = (const float*)d_in[0];   // [nS, 256] f32
    const int*   ssec = (const int*)d_in[1];     // [nS] i32
    const float* temb = (const float*)d_in[2];   // [nT, 256] f32
    const float* tsl  = (const float*)d_in[3];   // [nT] f32
    float* ws  = (float*)d_ws;
    float* out = (float*)d_out;
    const int nS = in_sizes[1];
    const int nT = in_sizes[3];

    hipLaunchKernelGGL(k_zero, dim3((WS_ZERO_FLOATS + 255) / 256), dim3(256), 0, stream, ws);
    hipLaunchKernelGGL(k_sums, dim3(1024), dim3(256), 0, stream, semb, ssec, ws, nS);
    hipLaunchKernelGGL(k_warm9, dim3(1024), dim3(256), 0, stream, temb, ws + WS_WARM, nT);
    hipLaunchKernelGGL(k_dist4, dim3(1024), dim3(256), 0, stream,
                       temb, tsl, ws, ws + WS_PART, nT);
    hipLaunchKernelGGL(k_final, dim3(1), dim3(1024), 0, stream,
                       ws + WS_PART, out, 1024, 1.0f / (float)nT);
}

// Round 15
// 103.949 us; speedup vs baseline: 2.2473x; 2.2473x over previous
//
#include <hip/hip_runtime.h>
#include <math.h>

#define D      256
#define NSEC   10
#define EPS    1e-6f
#define SLICE  0.1f

// ws float layout
#define WS_SUMS 0                        // [0,2560)    per-sector sums
#define WS_CNT  (NSEC * D)               // [2560,2570) per-sector counts
#define WS_CC   (NSEC * D + NSEC)        // [2570,5130) cc[s][d] = EPS - center
#define WS_PART (WS_CC + NSEC * D)       // [5130,6154) per-block partials (1024)
#define WS_ZERO_FLOATS (NSEC * D + NSEC)

__global__ void k_zero(float* __restrict__ ws) {
    int i = blockIdx.x * blockDim.x + threadIdx.x;
    if (i < WS_ZERO_FLOATS) ws[i] = 0.f;
}

// ---- k_sums: unchanged (proven 5.3 TB/s cold) ----
__global__ __launch_bounds__(256) void k_sums(const float* __restrict__ emb,
                                              const int* __restrict__ sec,
                                              float* __restrict__ ws, int nrows) {
    const int lane = threadIdx.x & 63;
    const int wid  = threadIdx.x >> 6;
    const int gw   = blockIdx.x * 4 + wid;
    const int nw   = gridDim.x * 4;

    float4 acc[NSEC];
    float  cnt[NSEC];
#pragma unroll
    for (int s = 0; s < NSEC; ++s) { acc[s] = make_float4(0.f, 0.f, 0.f, 0.f); cnt[s] = 0.f; }

    const float* ep = emb + (size_t)lane * 4;

    auto accum = [&](int sv, float4 v) {
        const int s = __builtin_amdgcn_readfirstlane(sv);
#pragma unroll
        for (int ss = 0; ss < NSEC; ++ss) {
            if (s == ss) {
                acc[ss].x += v.x; acc[ss].y += v.y; acc[ss].z += v.z; acc[ss].w += v.w;
                cnt[ss] += 1.f;
            }
        }
    };

    int r = gw;
    for (; r + 3 * nw < nrows; r += 4 * nw) {
        const int s0 = sec[r];
        const int s1 = sec[r + nw];
        const int s2 = sec[r + 2 * nw];
        const int s3 = sec[r + 3 * nw];
        const float4 v0 = *reinterpret_cast<const float4*>(ep + (size_t)r * D);
        const float4 v1 = *reinterpret_cast<const float4*>(ep + (size_t)(r + nw) * D);
        const float4 v2 = *reinterpret_cast<const float4*>(ep + (size_t)(r + 2 * nw) * D);
        const float4 v3 = *reinterpret_cast<const float4*>(ep + (size_t)(r + 3 * nw) * D);
        accum(s0, v0); accum(s1, v1); accum(s2, v2); accum(s3, v3);
    }
    for (; r < nrows; r += nw)
        accum(sec[r], *reinterpret_cast<const float4*>(ep + (size_t)r * D));

    __shared__ float lsum[NSEC * D];
    __shared__ float lcnt[NSEC];
    for (int i = threadIdx.x; i < NSEC * D; i += 256) lsum[i] = 0.f;
    if (threadIdx.x < NSEC) lcnt[threadIdx.x] = 0.f;
    __syncthreads();

    for (int w = 0; w < 4; ++w) {
        if (wid == w) {
#pragma unroll
            for (int ss = 0; ss < NSEC; ++ss) {
                float* p = &lsum[ss * D + lane * 4];
                p[0] += acc[ss].x; p[1] += acc[ss].y; p[2] += acc[ss].z; p[3] += acc[ss].w;
                if (lane == 0) lcnt[ss] += cnt[ss];
            }
        }
        __syncthreads();
    }

#pragma unroll
    for (int ss = 0; ss < NSEC; ++ss)
        atomicAdd(&ws[WS_SUMS + ss * D + threadIdx.x], lsum[ss * D + threadIdx.x]);
    if (threadIdx.x < NSEC)
        atomicAdd(&ws[WS_CNT + threadIdx.x], lcnt[threadIdx.x]);
}

// cc[s][d] = EPS - sums[s][d]/cnt[s]  (so distance term is v + cc)
__global__ __launch_bounds__(256) void k_cc(float* __restrict__ ws) {
    const int t = threadIdx.x;
    __shared__ float inv[NSEC];
    if (t < NSEC) inv[t] = 1.f / ws[WS_CNT + t];
    __syncthreads();
#pragma unroll
    for (int s = 0; s < NSEC; ++s)
        ws[WS_CC + s * D + t] = EPS - ws[WS_SUMS + s * D + t] * inv[s];
}

// k_dist5: k_sums' EXACT hot-loop structure. Centers in 40 REGISTERS (10-way
// compile-time branch, like k_sums' acc). Hot loop: global loads + wave-uniform
// scalar branch + FMA + one conflict-free wave-private ds_write. ZERO LDS reads,
// ZERO shuffles per row. Reduce+sqrt amortized once per 32-row group.
__global__ __launch_bounds__(256, 4) void k_dist5(const float* __restrict__ temb,
                                                  const float* __restrict__ tsl,
                                                  const float* __restrict__ ws,
                                                  float* __restrict__ part, int nrows) {
    const int lane = threadIdx.x & 63;
    const int wid  = threadIdx.x >> 6;
    const int gw   = blockIdx.x * 4 + wid;
    const int nw   = gridDim.x * 4;

    // register-resident pre-negated centers: lane's 4-dim slice of all 10 sectors
    float4 cr[NSEC];
#pragma unroll
    for (int ss = 0; ss < NSEC; ++ss)
        cr[ss] = *reinterpret_cast<const float4*>(&ws[WS_CC + ss * D + lane * 4]);

    __shared__ float pl[4][32 * 65];     // wave-private slabs, (row+i)%32 banks
    __shared__ float bsum[4];
    float* P = pl[wid];

    const float* tp = temb + (size_t)lane * 4;

    auto rowp = [&](int i, int ok, float si) -> void {};  // (placeholder, unused)

    float wacc = 0.f;
    // wave's rows: r = gw + i*nw. Process in groups of 32 rows; epilogue per group.
    for (int i0 = 0; gw + (size_t)i0 * nw < (size_t)nrows; i0 += 32) {
        // fill slab: 32 rows, 4 at a time (k_sums' batched pattern)
#pragma unroll 1
        for (int j = 0; j < 32; j += 4) {
            int   rr[4], ok[4];
            float t4[4];
            float4 v4[4];
#pragma unroll
            for (int k = 0; k < 4; ++k) {
                const int i = i0 + j + k;
                const int r = gw + i * nw;
                ok[k] = r < nrows;
                rr[k] = ok[k] ? r : nrows - 1;
                t4[k] = tsl[rr[k]];                    // wave-uniform broadcast
            }
#pragma unroll
            for (int k = 0; k < 4; ++k)
                v4[k] = *reinterpret_cast<const float4*>(tp + (size_t)rr[k] * D);

#pragma unroll
            for (int k = 0; k < 4; ++k) {
                int sv = (int)floorf(t4[k] / SLICE);   // exact reference semantics
                sv = sv < 0 ? 0 : (sv > NSEC - 1 ? NSEC - 1 : sv);
                const int s = __builtin_amdgcn_readfirstlane(sv);  // SGPR branch
                float p = 0.f;
#pragma unroll
                for (int ss = 0; ss < NSEC; ++ss) {
                    if (s == ss) {                     // compile-time register index
                        const float dx = v4[k].x + cr[ss].x;
                        const float dy = v4[k].y + cr[ss].y;
                        const float dz = v4[k].z + cr[ss].z;
                        const float dw = v4[k].w + cr[ss].w;
                        p = dx * dx + dy * dy + dz * dz + dw * dw;
                    }
                }
                p = ok[k] ? p : 0.f;
                P[(j + k) * 65 + lane] = p;            // wave-private, no barrier
            }
        }

        // epilogue (once per 32 rows): transposed stride-65 reads, 2-way free
        const int lrow = lane & 31, half = lane >> 5;
        float a = 0.f;
        const float* Pr = &P[lrow * 65 + half * 32];
#pragma unroll
        for (int i = 0; i < 32; ++i) a += Pr[i];
        a += __shfl_xor(a, 32, 64);                    // join the two 32-dim halves
        float d = (half == 0) ? sqrtf(a) : 0.f;        // one sqrt per row
#pragma unroll
        for (int off = 16; off >= 1; off >>= 1) d += __shfl_xor(d, off, 64);
        wacc += d;                                     // lanes 0..31 all hold group sum
    }

    if (lane == 0) bsum[wid] = wacc;
    __syncthreads();
    if (threadIdx.x == 0)
        part[blockIdx.x] = bsum[0] + bsum[1] + bsum[2] + bsum[3];
}

__global__ __launch_bounds__(1024) void k_final(const float* __restrict__ part,
                                                float* __restrict__ out,
                                                int nparts, float invN) {
    float v = 0.f;
    for (int i = threadIdx.x; i < nparts; i += 1024) v += part[i];
#pragma unroll
    for (int off = 32; off >= 1; off >>= 1) v += __shfl_xor(v, off, 64);
    __shared__ float s16[16];
    if ((threadIdx.x & 63) == 0) s16[threadIdx.x >> 6] = v;
    __syncthreads();
    if (threadIdx.x == 0) {
        float tot = 0.f;
#pragma unroll
        for (int k = 0; k < 16; ++k) tot += s16[k];
        out[0] = tot * invN;
    }
}

extern "C" void kernel_launch(void* const* d_in, const int* in_sizes, int n_in,
                              void* d_out, int out_size, void* d_ws, size_t ws_size,
                              hipStream_t stream) {
    const float* semb = (const float*)d_in[0];   // [nS, 256] f32
    const int*   ssec = (const int*)d_in[1];     // [nS] i32
    const float* temb = (const float*)d_in[2];   // [nT, 256] f32
    const float* tsl  = (const float*)d_in[3];   // [nT] f32
    float* ws  = (float*)d_ws;
    float* out = (float*)d_out;
    const int nS = in_sizes[1];
    const int nT = in_sizes[3];

    hipLaunchKernelGGL(k_zero, dim3((WS_ZERO_FLOATS + 255) / 256), dim3(256), 0, stream, ws);
    hipLaunchKernelGGL(k_sums, dim3(1024), dim3(256), 0, stream, semb, ssec, ws, nS);
    hipLaunchKernelGGL(k_cc, dim3(1), dim3(256), 0, stream, ws);
    hipLaunchKernelGGL(k_dist5, dim3(1024), dim3(256), 0, stream,
                       temb, tsl, ws, ws + WS_PART, nT);
    hipLaunchKernelGGL(k_final, dim3(1), dim3(1024), 0, stream,
                       ws + WS_PART, out, 1024, 1.0f / (float)nT);
}